// Round 8
// baseline (1565.205 us; speedup 1.0000x reference)
//
#include <hip/hip_runtime.h>
#include <stdint.h>

#define NN 100000
#define NE 1600000
#define DD 128
#define CC 40

// ---------------- CSR build ----------------

__global__ void k_count(const int* __restrict__ dst, int* __restrict__ deg){
    int e = blockIdx.x * 256 + threadIdx.x;
    if (e < NE) atomicAdd(&deg[dst[e]], 1);
}

__global__ __launch_bounds__(1024) void k_scan(const int* __restrict__ deg,
                                               int* __restrict__ row_ptr,
                                               int* __restrict__ cursor){
    __shared__ int sums[1024];
    int t = threadIdx.x;
    const int CH = (NN + 1023) / 1024;   // 98
    int base = t * CH;
    int s = 0;
    for (int i = 0; i < CH; i++){ int idx = base + i; if (idx < NN) s += deg[idx]; }
    sums[t] = s; __syncthreads();
    for (int off = 1; off < 1024; off <<= 1){
        int v = (t >= off) ? sums[t - off] : 0;
        __syncthreads();
        sums[t] += v;
        __syncthreads();
    }
    int run = (t == 0) ? 0 : sums[t - 1];
    for (int i = 0; i < CH; i++){
        int idx = base + i;
        if (idx < NN){ row_ptr[idx] = run; cursor[idx] = run; run += deg[idx]; }
    }
    if (t == 1023) row_ptr[NN] = sums[1023];
}

__global__ void k_fill(const int* __restrict__ src, const int* __restrict__ dst,
                       int* __restrict__ cursor, int* __restrict__ eidx){
    int e = blockIdx.x * 256 + threadIdx.x;
    if (e < NE){ int p = atomicAdd(&cursor[dst[e]], 1); eidx[p] = src[e]; }
}

// ------------- fused SAGE layer (all f32): gather-mean + dual GEMM + bias ---
// block = 256 threads, 16 nodes. Wave w gathers rows 4w..4w+3 (64 lanes x 2
// features each). Then 128 out-features x 2 node-groups GEMM.

template<bool RELU>
__global__ __launch_bounds__(256) void k_layer(
    const float* __restrict__ hin, const int* __restrict__ row_ptr,
    const int* __restrict__ eidx,
    const float* __restrict__ Ws, const float* __restrict__ Wn,
    const float* __restrict__ bias, float* __restrict__ out)
{
    __shared__ float sS[16][DD];
    __shared__ float sN[16][DD];
    int tid = threadIdx.x;
    int node0 = blockIdx.x * 16;

    // stage self rows
    for (int i = tid; i < 16 * DD; i += 256){
        int r = i >> 7, c = i & 127;
        sS[r][c] = hin[(size_t)(node0 + r) * DD + c];
    }
    // gather-mean neighbors
    int wave = tid >> 6, lane = tid & 63;
    #pragma unroll
    for (int rr = 0; rr < 4; rr++){
        int r = wave * 4 + rr;
        int node = node0 + r;
        int beg = row_ptr[node], end = row_ptr[node + 1];
        float a0 = 0.f, a1 = 0.f;
        for (int i = beg; i < end; i++){
            int s = eidx[i];
            float2 v = *(const float2*)(hin + (size_t)s * DD + lane * 2);
            a0 += v.x; a1 += v.y;
        }
        int d = end - beg;
        float inv = 1.f / (float)(d > 1 ? d : 1);
        sN[r][lane * 2]     = a0 * inv;
        sN[r][lane * 2 + 1] = a1 * inv;
    }
    __syncthreads();

    // dual GEMM: out[r][f] = sum_k sS[r][k]*Ws[k][f] + sN[r][k]*Wn[k][f] + b[f]
    int f  = tid & 127;
    int ng = tid >> 7;
    float acc[8];
    #pragma unroll
    for (int j = 0; j < 8; j++) acc[j] = 0.f;
    #pragma unroll 2
    for (int k = 0; k < DD; k++){
        float ws = Ws[k * DD + f];
        float wn = Wn[k * DD + f];
        #pragma unroll
        for (int j = 0; j < 8; j++)
            acc[j] += sS[ng * 8 + j][k] * ws + sN[ng * 8 + j][k] * wn;
    }
    float bv = bias[f];
    #pragma unroll
    for (int j = 0; j < 8; j++){
        float v = acc[j] + bv;
        if (RELU) v = fmaxf(v, 0.f);
        out[(size_t)(node0 + ng * 8 + j) * DD + f] = v;
    }
}

// ---------------- final FC: logits = h @ fc_w + fc_b (all f32) --------------

__global__ void k_fc(const float* __restrict__ h, const float* __restrict__ W,
                     const float* __restrict__ b, float* __restrict__ out)
{
    int idx = blockIdx.x * 256 + threadIdx.x;     // NN*CC/256 exact
    int n = idx / CC, f = idx - n * CC;
    const float* hr = h + (size_t)n * DD;
    float acc = b[f];
    #pragma unroll 8
    for (int k = 0; k < DD; k++) acc += hr[k] * W[k * CC + f];
    out[idx] = acc;
}

extern "C" void kernel_launch(void* const* d_in, const int* in_sizes, int n_in,
                              void* d_out, int out_size, void* d_ws, size_t ws_size,
                              hipStream_t stream)
{
    const float* x   = (const float*)d_in[0];
    const int*   src = (const int*)d_in[1];
    const int*   dst = (const int*)d_in[2];
    const float* Ws0 = (const float*)d_in[3];
    const float* Wn0 = (const float*)d_in[4];
    const float* b0  = (const float*)d_in[5];
    const float* Ws1 = (const float*)d_in[6];
    const float* Wn1 = (const float*)d_in[7];
    const float* b1  = (const float*)d_in[8];
    const float* Ws2 = (const float*)d_in[9];
    const float* Wn2 = (const float*)d_in[10];
    const float* b2  = (const float*)d_in[11];
    const float* fcw = (const float*)d_in[12];
    const float* fcb = (const float*)d_in[13];
    float* out   = (float*)d_out;
    float* h_out = out + (size_t)NN * CC;   // h section of d_out (f32)

    // workspace layout: ~59 MB total
    char* ws = (char*)d_ws;
    int*   deg     = (int*)(ws);                           // 400 KB
    int*   row_ptr = (int*)(ws + (size_t)( 512u << 10));   // 400 KB
    int*   cursor  = (int*)(ws + (size_t)(1024u << 10));   // 400 KB
    int*   eidx    = (int*)(ws + (size_t)(1536u << 10));   // 6.4 MB -> ends 7.9 MB
    float* hA      = (float*)(ws + (size_t)(8u << 20));    // 51.2 MB -> ends 59.2 MB

    hipMemsetAsync(deg, 0, NN * sizeof(int), stream);
    k_count<<<(NE + 255) / 256, 256, 0, stream>>>(dst, deg);
    k_scan<<<1, 1024, 0, stream>>>(deg, row_ptr, cursor);
    k_fill<<<(NE + 255) / 256, 256, 0, stream>>>(src, dst, cursor, eidx);

    // layer 0: x -> h_out (relu)
    k_layer<true ><<<NN / 16, 256, 0, stream>>>(x,     row_ptr, eidx, Ws0, Wn0, b0, h_out);
    // layer 1: h_out -> hA (relu)
    k_layer<true ><<<NN / 16, 256, 0, stream>>>(h_out, row_ptr, eidx, Ws1, Wn1, b1, hA);
    // layer 2: hA -> h_out (no relu)
    k_layer<false><<<NN / 16, 256, 0, stream>>>(hA,    row_ptr, eidx, Ws2, Wn2, b2, h_out);

    // final FC -> logits section
    k_fc<<<NN * CC / 256, 256, 0, stream>>>(h_out, fcw, fcb, out);
}

// Round 10
// 1506.314 us; speedup vs baseline: 1.0391x; 1.0391x over previous
//
#include <hip/hip_runtime.h>
#include <stdint.h>

#define NN 100000
#define NE 1600000
#define DD 128
#define CC 40

typedef unsigned short u16;
typedef unsigned int   u32;
typedef __attribute__((ext_vector_type(8))) short short8;
typedef __attribute__((ext_vector_type(4))) float f32x4;

__device__ __forceinline__ float b2f(u16 u){ return __uint_as_float(((u32)u) << 16); }
__device__ __forceinline__ u16   f2b(float f){
    u32 i = __float_as_uint(f);
    u32 r = (i + 0x7FFFu + ((i >> 16) & 1u)) >> 16;   // round-nearest-even
    return (u16)r;
}

// LDS tile: 32 rows x 512 bytes (256 bf16 k-slots). XOR swizzle breaks the
// 512B-stride bank pattern on ds_read_b128 (T2); writers/reader share this.
__device__ __forceinline__ int swz(int row, int byte_in_row){
    return row * 512 + (byte_in_row ^ ((row & 7) << 4));
}

// ---------------- CSR build (proven round 8) ----------------

__global__ void k_count(const int* __restrict__ dst, int* __restrict__ deg){
    int e = blockIdx.x * 256 + threadIdx.x;
    if (e < NE) atomicAdd(&deg[dst[e]], 1);
}

__global__ __launch_bounds__(1024) void k_scan(const int* __restrict__ deg,
                                               int* __restrict__ row_ptr,
                                               int* __restrict__ cursor){
    __shared__ int sums[1024];
    int t = threadIdx.x;
    const int CH = (NN + 1023) / 1024;   // 98
    int base = t * CH;
    int s = 0;
    for (int i = 0; i < CH; i++){ int idx = base + i; if (idx < NN) s += deg[idx]; }
    sums[t] = s; __syncthreads();
    for (int off = 1; off < 1024; off <<= 1){
        int v = (t >= off) ? sums[t - off] : 0;
        __syncthreads();
        sums[t] += v;
        __syncthreads();
    }
    int run = (t == 0) ? 0 : sums[t - 1];
    for (int i = 0; i < CH; i++){
        int idx = base + i;
        if (idx < NN){ row_ptr[idx] = run; cursor[idx] = run; run += deg[idx]; }
    }
    if (t == 1023) row_ptr[NN] = sums[1023];
}

__global__ void k_fill(const int* __restrict__ src, const int* __restrict__ dst,
                       int* __restrict__ cursor, int* __restrict__ eidx){
    int e = blockIdx.x * 256 + threadIdx.x;
    if (e < NE){ int p = atomicAdd(&cursor[dst[e]], 1); eidx[p] = src[e]; }
}

// ---------------- x (f32) -> bf16 copy, 8 elems/thread ----------------------

__global__ __launch_bounds__(256) void k_cvt(const float* __restrict__ x,
                                             u16* __restrict__ xb){
    size_t i = ((size_t)blockIdx.x * 256 + threadIdx.x) * 8;
    float4 v0 = *(const float4*)(x + i);
    float4 v1 = *(const float4*)(x + i + 4);
    u32 w0 = (u32)f2b(v0.x) | ((u32)f2b(v0.y) << 16);
    u32 w1 = (u32)f2b(v0.z) | ((u32)f2b(v0.w) << 16);
    u32 w2 = (u32)f2b(v1.x) | ((u32)f2b(v1.y) << 16);
    u32 w3 = (u32)f2b(v1.z) | ((u32)f2b(v1.w) << 16);
    uint4 o = {w0, w1, w2, w3};
    *(uint4*)(xb + i) = o;
}

// ------- weight prep: Wt[f][k] bf16, k<128 = Ws[k][f], k>=128 = Wn[k-128][f] -

__global__ __launch_bounds__(256) void k_wprep(const float* __restrict__ Ws,
                                               const float* __restrict__ Wn,
                                               u16* __restrict__ Wt){
    int id = blockIdx.x * 256 + threadIdx.x;   // 0 .. 128*256-1
    int f = id >> 8, k = id & 255;
    float v = (k < 128) ? Ws[k * DD + f] : Wn[(k - 128) * DD + f];
    Wt[f * 256 + k] = f2b(v);
}

// ------------- fused SAGE layer: gather-mean + MFMA GEMM + bias (+relu) -----
// block = 256 threads = 4 waves, 32 nodes. A = [self | neigh-mean] (32x256
// bf16, LDS, swizzled). B = Wt (256x128 bf16, L2). K=256 in 8 MFMA k-steps.

template<bool RELU, bool OUTF32>
__global__ __launch_bounds__(256) void k_layer(
    const u16* __restrict__ hin, const int* __restrict__ row_ptr,
    const int* __restrict__ eidx, const u16* __restrict__ Wt,
    const float* __restrict__ bias, void* __restrict__ outp)
{
    __shared__ uint4 lds4[1024];            // 16 KB
    char* lds = (char*)lds4;
    int tid = threadIdx.x;
    int node0 = blockIdx.x * 32;

    // stage self rows (bf16, 16B chunks) into k=0..127 (bytes 0..255)
    for (int c = tid; c < 512; c += 256){
        int r = c >> 4, ci = c & 15;
        uint4 v = *(const uint4*)(hin + (size_t)(node0 + r) * DD + ci * 8);
        *(uint4*)(lds + swz(r, ci * 16)) = v;
    }
    // gather-mean neighbors: wave w -> rows 8w..8w+7; lane covers 2 features.
    // k = 128 + 2*lane lives at BYTE 256 + 4*lane (round-9 bug: was 512+).
    int wave = tid >> 6, lane = tid & 63;
    for (int rr = 0; rr < 8; rr++){
        int r = wave * 8 + rr;
        int node = node0 + r;
        int beg = row_ptr[node], end = row_ptr[node + 1];
        float a0 = 0.f, a1 = 0.f;
        for (int i = beg; i < end; i++){
            int s = eidx[i];
            u32 u = *(const u32*)(hin + (size_t)s * DD + lane * 2);
            a0 += b2f((u16)(u & 0xFFFFu));
            a1 += b2f((u16)(u >> 16));
        }
        int d = end - beg;
        float inv = 1.f / (float)(d > 1 ? d : 1);
        u32 o = (u32)f2b(a0 * inv) | ((u32)f2b(a1 * inv) << 16);
        *(u32*)(lds + swz(r, 256 + lane * 4)) = o;
    }
    __syncthreads();

    // MFMA GEMM: wave w -> node-tile (w&1), feature-tiles (w>>1)*4 .. +3
    int nt = wave & 1, fgrp = wave >> 1;
    int lrow = lane & 15, lk = lane >> 4;
    f32x4 acc0 = {0.f,0.f,0.f,0.f}, acc1 = acc0, acc2 = acc0, acc3 = acc0;
    #pragma unroll
    for (int kk = 0; kk < 8; kk++){
        int k0 = kk * 32 + lk * 8;
        short8 a = *(const short8*)(lds + swz(nt * 16 + lrow, k0 * 2));
        const short* wb = (const short*)Wt + k0;
        short8 b0 = *(const short8*)(wb + (size_t)((fgrp * 4 + 0) * 16 + lrow) * 256);
        short8 b1 = *(const short8*)(wb + (size_t)((fgrp * 4 + 1) * 16 + lrow) * 256);
        short8 b2 = *(const short8*)(wb + (size_t)((fgrp * 4 + 2) * 16 + lrow) * 256);
        short8 b3 = *(const short8*)(wb + (size_t)((fgrp * 4 + 3) * 16 + lrow) * 256);
        acc0 = __builtin_amdgcn_mfma_f32_16x16x32_bf16(a, b0, acc0, 0, 0, 0);
        acc1 = __builtin_amdgcn_mfma_f32_16x16x32_bf16(a, b1, acc1, 0, 0, 0);
        acc2 = __builtin_amdgcn_mfma_f32_16x16x32_bf16(a, b2, acc2, 0, 0, 0);
        acc3 = __builtin_amdgcn_mfma_f32_16x16x32_bf16(a, b3, acc3, 0, 0, 0);
    }
    // epilogue: C/D layout col = lane&15, row = (lane>>4)*4 + reg  [m89]
    int base_row = node0 + nt * 16 + lk * 4;
    #pragma unroll
    for (int ft = 0; ft < 4; ft++){
        f32x4 acc = (ft == 0) ? acc0 : (ft == 1) ? acc1 : (ft == 2) ? acc2 : acc3;
        int col = (fgrp * 4 + ft) * 16 + lrow;
        float bv = bias[col];
        #pragma unroll
        for (int t = 0; t < 4; t++){
            float v = acc[t] + bv;
            if (RELU) v = fmaxf(v, 0.f);
            size_t off = (size_t)(base_row + t) * DD + col;
            if (OUTF32) ((float*)outp)[off] = v;
            else        ((u16*)outp)[off]   = f2b(v);
        }
    }
}

// ---------------- final FC: logits = h @ fc_w + fc_b (all f32, proven) ------

__global__ void k_fc(const float* __restrict__ h, const float* __restrict__ W,
                     const float* __restrict__ b, float* __restrict__ out)
{
    int idx = blockIdx.x * 256 + threadIdx.x;     // NN*CC/256 exact
    int n = idx / CC, f = idx - n * CC;
    const float* hr = h + (size_t)n * DD;
    float acc = b[f];
    #pragma unroll 8
    for (int k = 0; k < DD; k++) acc += hr[k] * W[k * CC + f];
    out[idx] = acc;
}

extern "C" void kernel_launch(void* const* d_in, const int* in_sizes, int n_in,
                              void* d_out, int out_size, void* d_ws, size_t ws_size,
                              hipStream_t stream)
{
    const float* x   = (const float*)d_in[0];
    const int*   src = (const int*)d_in[1];
    const int*   dst = (const int*)d_in[2];
    const float* Ws0 = (const float*)d_in[3];
    const float* Wn0 = (const float*)d_in[4];
    const float* b0  = (const float*)d_in[5];
    const float* Ws1 = (const float*)d_in[6];
    const float* Wn1 = (const float*)d_in[7];
    const float* b1  = (const float*)d_in[8];
    const float* Ws2 = (const float*)d_in[9];
    const float* Wn2 = (const float*)d_in[10];
    const float* b2  = (const float*)d_in[11];
    const float* fcw = (const float*)d_in[12];
    const float* fcb = (const float*)d_in[13];
    float* out    = (float*)d_out;
    float* hout32 = out + (size_t)NN * CC;   // h section of d_out (f32)

    // workspace layout: ~61.6 MB total
    char* ws = (char*)d_ws;
    int* deg     = (int*)(ws);                           // 400 KB
    int* row_ptr = (int*)(ws + (size_t)( 512u << 10));   // 400 KB
    int* cursor  = (int*)(ws + (size_t)(1024u << 10));   // 400 KB
    int* eidx    = (int*)(ws + (size_t)(1536u << 10));   // 6.4 MB -> ends 7.9 MB
    u16* Wt0     = (u16*)(ws + (size_t)(8u << 20));              // 64 KB
    u16* Wt1     = (u16*)(ws + (size_t)(8u << 20) + 65536);      // 64 KB
    u16* Wt2     = (u16*)(ws + (size_t)(8u << 20) + 131072);     // 64 KB
    u16* h1      = (u16*)(ws + (size_t)( 9u << 20));   // 25.6 MB -> ends 34.6 MB
    u16* h2      = (u16*)(ws + (size_t)(36u << 20));   // 25.6 MB -> ends 61.6 MB
    u16* x_bf    = h2;   // x_bf dead after layer 0; layer 1 then overwrites h2

    // CSR build
    hipMemsetAsync(deg, 0, NN * sizeof(int), stream);
    k_count<<<(NE + 255) / 256, 256, 0, stream>>>(dst, deg);
    k_scan<<<1, 1024, 0, stream>>>(deg, row_ptr, cursor);
    k_fill<<<(NE + 255) / 256, 256, 0, stream>>>(src, dst, cursor, eidx);

    // input conversion + weight prep
    k_cvt<<<NN * DD / 8 / 256, 256, 0, stream>>>(x, x_bf);
    k_wprep<<<DD * 256 / 256, 256, 0, stream>>>(Ws0, Wn0, Wt0);
    k_wprep<<<DD * 256 / 256, 256, 0, stream>>>(Ws1, Wn1, Wt1);
    k_wprep<<<DD * 256 / 256, 256, 0, stream>>>(Ws2, Wn2, Wt2);

    // layer 0: x_bf -> h1 (relu, bf16)
    k_layer<true,  false><<<NN / 32, 256, 0, stream>>>(x_bf, row_ptr, eidx, Wt0, b0, h1);
    // layer 1: h1 -> h2 (relu, bf16; overwrites x_bf which is now dead)
    k_layer<true,  false><<<NN / 32, 256, 0, stream>>>(h1, row_ptr, eidx, Wt1, b1, h2);
    // layer 2: h2 -> d_out h section (no relu, f32)
    k_layer<false, true ><<<NN / 32, 256, 0, stream>>>(h2, row_ptr, eidx, Wt2, b2, hout32);

    // final FC -> logits section
    k_fc<<<NN * CC / 256, 256, 0, stream>>>(hout32, fcw, fcb, out);
}

// Round 11
// 1055.491 us; speedup vs baseline: 1.4829x; 1.4271x over previous
//
#include <hip/hip_runtime.h>
#include <stdint.h>

#define NN 100000
#define NE 1600000
#define DD 128
#define CC 40

typedef unsigned short u16;
typedef unsigned int   u32;
typedef __attribute__((ext_vector_type(8))) short short8;
typedef __attribute__((ext_vector_type(4))) float f32x4;

__device__ __forceinline__ float b2f(u16 u){ return __uint_as_float(((u32)u) << 16); }
__device__ __forceinline__ u16   f2b(float f){
    u32 i = __float_as_uint(f);
    u32 r = (i + 0x7FFFu + ((i >> 16) & 1u)) >> 16;   // round-nearest-even
    return (u16)r;
}

// LDS tile: 32 rows x 512 bytes (256 bf16 k-slots). XOR swizzle breaks the
// 512B-stride bank pattern on ds_read_b128 (T2); writers/reader share this.
__device__ __forceinline__ int swz(int row, int byte_in_row){
    return row * 512 + (byte_in_row ^ ((row & 7) << 4));
}

// ---------------- CSR build (proven round 8) ----------------

__global__ void k_count(const int* __restrict__ dst, int* __restrict__ deg){
    int e = blockIdx.x * 256 + threadIdx.x;
    if (e < NE) atomicAdd(&deg[dst[e]], 1);
}

__global__ __launch_bounds__(1024) void k_scan(const int* __restrict__ deg,
                                               int* __restrict__ row_ptr,
                                               int* __restrict__ cursor){
    __shared__ int sums[1024];
    int t = threadIdx.x;
    const int CH = (NN + 1023) / 1024;   // 98
    int base = t * CH;
    int s = 0;
    for (int i = 0; i < CH; i++){ int idx = base + i; if (idx < NN) s += deg[idx]; }
    sums[t] = s; __syncthreads();
    for (int off = 1; off < 1024; off <<= 1){
        int v = (t >= off) ? sums[t - off] : 0;
        __syncthreads();
        sums[t] += v;
        __syncthreads();
    }
    int run = (t == 0) ? 0 : sums[t - 1];
    for (int i = 0; i < CH; i++){
        int idx = base + i;
        if (idx < NN){ row_ptr[idx] = run; cursor[idx] = run; run += deg[idx]; }
    }
    if (t == 1023) row_ptr[NN] = sums[1023];
}

__global__ void k_fill(const int* __restrict__ src, const int* __restrict__ dst,
                       int* __restrict__ cursor, int* __restrict__ eidx){
    int e = blockIdx.x * 256 + threadIdx.x;
    if (e < NE){ int p = atomicAdd(&cursor[dst[e]], 1); eidx[p] = src[e]; }
}

// ---------------- x (f32) -> bf16 copy, 8 elems/thread ----------------------

__global__ __launch_bounds__(256) void k_cvt(const float* __restrict__ x,
                                             u16* __restrict__ xb){
    size_t i = ((size_t)blockIdx.x * 256 + threadIdx.x) * 8;
    float4 v0 = *(const float4*)(x + i);
    float4 v1 = *(const float4*)(x + i + 4);
    u32 w0 = (u32)f2b(v0.x) | ((u32)f2b(v0.y) << 16);
    u32 w1 = (u32)f2b(v0.z) | ((u32)f2b(v0.w) << 16);
    u32 w2 = (u32)f2b(v1.x) | ((u32)f2b(v1.y) << 16);
    u32 w3 = (u32)f2b(v1.z) | ((u32)f2b(v1.w) << 16);
    uint4 o = {w0, w1, w2, w3};
    *(uint4*)(xb + i) = o;
}

// ------- weight prep: Wt[f][k] bf16, k<128 = Ws[k][f], k>=128 = Wn[k-128][f] -

__global__ __launch_bounds__(256) void k_wprep(const float* __restrict__ Ws,
                                               const float* __restrict__ Wn,
                                               u16* __restrict__ Wt){
    int id = blockIdx.x * 256 + threadIdx.x;   // 0 .. 128*256-1
    int f = id >> 8, k = id & 255;
    float v = (k < 128) ? Ws[k * DD + f] : Wn[(k - 128) * DD + f];
    Wt[f * 256 + k] = f2b(v);
}

// ------------- fused SAGE layer: gather-mean + MFMA GEMM + bias (+relu) -----
// block = 256 threads = 4 waves, 32 nodes. A = [self | neigh-mean] (32x256
// bf16, LDS, swizzled). B = Wt (256x128 bf16, L2). K=256 in 8 MFMA k-steps.
// Gather uses readlane-broadcast + 8-deep load unroll for MLP (round-11).

template<bool RELU, bool OUTF32>
__global__ __launch_bounds__(256) void k_layer(
    const u16* __restrict__ hin, const int* __restrict__ row_ptr,
    const int* __restrict__ eidx, const u16* __restrict__ Wt,
    const float* __restrict__ bias, void* __restrict__ outp)
{
    __shared__ uint4 lds4[1024];            // 16 KB
    char* lds = (char*)lds4;
    int tid = threadIdx.x;
    int node0 = blockIdx.x * 32;

    // stage self rows (bf16, 16B chunks) into k=0..127 (bytes 0..255)
    for (int c = tid; c < 512; c += 256){
        int r = c >> 4, ci = c & 15;
        uint4 v = *(const uint4*)(hin + (size_t)(node0 + r) * DD + ci * 8);
        *(uint4*)(lds + swz(r, ci * 16)) = v;
    }
    // gather-mean neighbors: wave w -> rows 8w..8w+7; lane covers 2 features.
    int wave = tid >> 6, lane = tid & 63;
    for (int rr = 0; rr < 8; rr++){
        int r = wave * 8 + rr;
        int node = node0 + r;
        int beg = row_ptr[node], end = row_ptr[node + 1];
        float a0 = 0.f, a1 = 0.f;
        for (int cb = beg; cb < end; cb += 64){
            int rem = end - cb;
            int cnt = rem < 64 ? rem : 64;
            // all lanes pre-load up to 64 neighbor ids (1 vector load)
            int my_e = eidx[cb + (lane < cnt ? lane : cnt - 1)];
            int j = 0;
            for (; j + 8 <= cnt; j += 8){
                int s0 = __builtin_amdgcn_readlane(my_e, j + 0);
                int s1 = __builtin_amdgcn_readlane(my_e, j + 1);
                int s2 = __builtin_amdgcn_readlane(my_e, j + 2);
                int s3 = __builtin_amdgcn_readlane(my_e, j + 3);
                int s4 = __builtin_amdgcn_readlane(my_e, j + 4);
                int s5 = __builtin_amdgcn_readlane(my_e, j + 5);
                int s6 = __builtin_amdgcn_readlane(my_e, j + 6);
                int s7 = __builtin_amdgcn_readlane(my_e, j + 7);
                u32 u0 = *(const u32*)(hin + (size_t)s0 * DD + lane * 2);
                u32 u1 = *(const u32*)(hin + (size_t)s1 * DD + lane * 2);
                u32 u2 = *(const u32*)(hin + (size_t)s2 * DD + lane * 2);
                u32 u3 = *(const u32*)(hin + (size_t)s3 * DD + lane * 2);
                u32 u4 = *(const u32*)(hin + (size_t)s4 * DD + lane * 2);
                u32 u5 = *(const u32*)(hin + (size_t)s5 * DD + lane * 2);
                u32 u6 = *(const u32*)(hin + (size_t)s6 * DD + lane * 2);
                u32 u7 = *(const u32*)(hin + (size_t)s7 * DD + lane * 2);
                a0 += ((b2f((u16)(u0 & 0xFFFFu)) + b2f((u16)(u1 & 0xFFFFu))) +
                       (b2f((u16)(u2 & 0xFFFFu)) + b2f((u16)(u3 & 0xFFFFu)))) +
                      ((b2f((u16)(u4 & 0xFFFFu)) + b2f((u16)(u5 & 0xFFFFu))) +
                       (b2f((u16)(u6 & 0xFFFFu)) + b2f((u16)(u7 & 0xFFFFu))));
                a1 += ((b2f((u16)(u0 >> 16)) + b2f((u16)(u1 >> 16))) +
                       (b2f((u16)(u2 >> 16)) + b2f((u16)(u3 >> 16)))) +
                      ((b2f((u16)(u4 >> 16)) + b2f((u16)(u5 >> 16))) +
                       (b2f((u16)(u6 >> 16)) + b2f((u16)(u7 >> 16))));
            }
            for (; j < cnt; j++){
                int s = __builtin_amdgcn_readlane(my_e, j);
                u32 u = *(const u32*)(hin + (size_t)s * DD + lane * 2);
                a0 += b2f((u16)(u & 0xFFFFu));
                a1 += b2f((u16)(u >> 16));
            }
        }
        int d = end - beg;
        float inv = 1.f / (float)(d > 1 ? d : 1);
        u32 o = (u32)f2b(a0 * inv) | ((u32)f2b(a1 * inv) << 16);
        *(u32*)(lds + swz(r, 256 + lane * 4)) = o;   // k = 128+2*lane at byte 256+4*lane
    }
    __syncthreads();

    // MFMA GEMM: wave w -> node-tile (w&1), feature-tiles (w>>1)*4 .. +3
    int nt = wave & 1, fgrp = wave >> 1;
    int lrow = lane & 15, lk = lane >> 4;
    f32x4 acc0 = {0.f,0.f,0.f,0.f}, acc1 = acc0, acc2 = acc0, acc3 = acc0;
    #pragma unroll
    for (int kk = 0; kk < 8; kk++){
        int k0 = kk * 32 + lk * 8;
        short8 a = *(const short8*)(lds + swz(nt * 16 + lrow, k0 * 2));
        const short* wb = (const short*)Wt + k0;
        short8 b0 = *(const short8*)(wb + (size_t)((fgrp * 4 + 0) * 16 + lrow) * 256);
        short8 b1 = *(const short8*)(wb + (size_t)((fgrp * 4 + 1) * 16 + lrow) * 256);
        short8 b2 = *(const short8*)(wb + (size_t)((fgrp * 4 + 2) * 16 + lrow) * 256);
        short8 b3 = *(const short8*)(wb + (size_t)((fgrp * 4 + 3) * 16 + lrow) * 256);
        acc0 = __builtin_amdgcn_mfma_f32_16x16x32_bf16(a, b0, acc0, 0, 0, 0);
        acc1 = __builtin_amdgcn_mfma_f32_16x16x32_bf16(a, b1, acc1, 0, 0, 0);
        acc2 = __builtin_amdgcn_mfma_f32_16x16x32_bf16(a, b2, acc2, 0, 0, 0);
        acc3 = __builtin_amdgcn_mfma_f32_16x16x32_bf16(a, b3, acc3, 0, 0, 0);
    }
    // epilogue: C/D layout col = lane&15, row = (lane>>4)*4 + reg  [m89]
    int base_row = node0 + nt * 16 + lk * 4;
    #pragma unroll
    for (int ft = 0; ft < 4; ft++){
        f32x4 acc = (ft == 0) ? acc0 : (ft == 1) ? acc1 : (ft == 2) ? acc2 : acc3;
        int col = (fgrp * 4 + ft) * 16 + lrow;
        float bv = bias[col];
        #pragma unroll
        for (int t = 0; t < 4; t++){
            float v = acc[t] + bv;
            if (RELU) v = fmaxf(v, 0.f);
            size_t off = (size_t)(base_row + t) * DD + col;
            if (OUTF32) ((float*)outp)[off] = v;
            else        ((u16*)outp)[off]   = f2b(v);
        }
    }
}

// ---------------- final FC: logits = h @ fc_w + fc_b (all f32, proven) ------

__global__ void k_fc(const float* __restrict__ h, const float* __restrict__ W,
                     const float* __restrict__ b, float* __restrict__ out)
{
    int idx = blockIdx.x * 256 + threadIdx.x;     // NN*CC/256 exact
    int n = idx / CC, f = idx - n * CC;
    const float* hr = h + (size_t)n * DD;
    float acc = b[f];
    #pragma unroll 8
    for (int k = 0; k < DD; k++) acc += hr[k] * W[k * CC + f];
    out[idx] = acc;
}

extern "C" void kernel_launch(void* const* d_in, const int* in_sizes, int n_in,
                              void* d_out, int out_size, void* d_ws, size_t ws_size,
                              hipStream_t stream)
{
    const float* x   = (const float*)d_in[0];
    const int*   src = (const int*)d_in[1];
    const int*   dst = (const int*)d_in[2];
    const float* Ws0 = (const float*)d_in[3];
    const float* Wn0 = (const float*)d_in[4];
    const float* b0  = (const float*)d_in[5];
    const float* Ws1 = (const float*)d_in[6];
    const float* Wn1 = (const float*)d_in[7];
    const float* b1  = (const float*)d_in[8];
    const float* Ws2 = (const float*)d_in[9];
    const float* Wn2 = (const float*)d_in[10];
    const float* b2  = (const float*)d_in[11];
    const float* fcw = (const float*)d_in[12];
    const float* fcb = (const float*)d_in[13];
    float* out    = (float*)d_out;
    float* hout32 = out + (size_t)NN * CC;   // h section of d_out (f32)

    // workspace layout: ~61.6 MB total
    char* ws = (char*)d_ws;
    int* deg     = (int*)(ws);                           // 400 KB
    int* row_ptr = (int*)(ws + (size_t)( 512u << 10));   // 400 KB
    int* cursor  = (int*)(ws + (size_t)(1024u << 10));   // 400 KB
    int* eidx    = (int*)(ws + (size_t)(1536u << 10));   // 6.4 MB -> ends 7.9 MB
    u16* Wt0     = (u16*)(ws + (size_t)(8u << 20));              // 64 KB
    u16* Wt1     = (u16*)(ws + (size_t)(8u << 20) + 65536);      // 64 KB
    u16* Wt2     = (u16*)(ws + (size_t)(8u << 20) + 131072);     // 64 KB
    u16* h1      = (u16*)(ws + (size_t)( 9u << 20));   // 25.6 MB -> ends 34.6 MB
    u16* h2      = (u16*)(ws + (size_t)(36u << 20));   // 25.6 MB -> ends 61.6 MB
    u16* x_bf    = h2;   // x_bf dead after layer 0; layer 1 then overwrites h2

    // CSR build
    hipMemsetAsync(deg, 0, NN * sizeof(int), stream);
    k_count<<<(NE + 255) / 256, 256, 0, stream>>>(dst, deg);
    k_scan<<<1, 1024, 0, stream>>>(deg, row_ptr, cursor);
    k_fill<<<(NE + 255) / 256, 256, 0, stream>>>(src, dst, cursor, eidx);

    // input conversion + weight prep
    k_cvt<<<NN * DD / 8 / 256, 256, 0, stream>>>(x, x_bf);
    k_wprep<<<DD * 256 / 256, 256, 0, stream>>>(Ws0, Wn0, Wt0);
    k_wprep<<<DD * 256 / 256, 256, 0, stream>>>(Ws1, Wn1, Wt1);
    k_wprep<<<DD * 256 / 256, 256, 0, stream>>>(Ws2, Wn2, Wt2);

    // layer 0: x_bf -> h1 (relu, bf16)
    k_layer<true,  false><<<NN / 32, 256, 0, stream>>>(x_bf, row_ptr, eidx, Wt0, b0, h1);
    // layer 1: h1 -> h2 (relu, bf16; overwrites x_bf which is now dead)
    k_layer<true,  false><<<NN / 32, 256, 0, stream>>>(h1, row_ptr, eidx, Wt1, b1, h2);
    // layer 2: h2 -> d_out h section (no relu, f32)
    k_layer<false, true ><<<NN / 32, 256, 0, stream>>>(h2, row_ptr, eidx, Wt2, b2, hout32);

    // final FC -> logits section
    k_fc<<<NN * CC / 256, 256, 0, stream>>>(hout32, fcw, fcb, out);
}